// Round 10
// baseline (421.104 us; speedup 1.0000x reference)
//
#include <hip/hip_runtime.h>
#include <hip/hip_bf16.h>

#define B_ 2
#define T_ 2048
#define C_ 1280
#define H_ 10
#define D_ 128
#define BT_ (B_*T_)

typedef __hip_bfloat16 bf16;
typedef __attribute__((ext_vector_type(8))) short short8;
typedef __attribute__((ext_vector_type(4))) float f32x4;

__device__ __forceinline__ float bf2f(bf16 v){ return __bfloat162float(v); }
__device__ __forceinline__ bf16  f2bf(float v){ return __float2bfloat16(v); }

struct alignas(8) bf4 { bf16 a,b,c,d; };

__device__ __forceinline__ void gl2lds(const bf16* g, bf16* l) {
    __builtin_amdgcn_global_load_lds(
        (const __attribute__((address_space(1))) void*)g,
        (__attribute__((address_space(3))) void*)l,
        16, 0, 0);
}

// ---- fused fp32->bf16 convert: x (5120 blocks) + 4 weight mats (1600 each).
// Block 0 additionally zeroes the 480 combine tickets (runs before attn). ----
__global__ __launch_bounds__(256)
void cvtall(const float* __restrict__ x,  const float* __restrict__ w0,
            const float* __restrict__ w1, const float* __restrict__ w2,
            const float* __restrict__ w3, bf16* __restrict__ xb,
            bf16* __restrict__ wb, int* __restrict__ cnt)
{
    int bid = blockIdx.x;
    if (bid == 0) {
        cnt[threadIdx.x] = 0;
        if (threadIdx.x + 256 < 480) cnt[threadIdx.x + 256] = 0;
    }
    const float* s; bf16* d; int i;
    if (bid < 5120) {
        s = x; d = xb; i = (bid*256 + threadIdx.x)*4;
    } else {
        bid -= 5120;
        const int w = bid / 1600;
        const int r = bid % 1600;
        s = (w==0)?w0:(w==1)?w1:(w==2)?w2:w3;
        d = wb + (size_t)w*C_*C_;
        i = (r*256 + threadIdx.x)*4;
    }
    const float4 v = *(const float4*)(s + i);
    bf4 o = { f2bf(v.x), f2bf(v.y), f2bf(v.z), f2bf(v.w) };
    *(bf4*)(d + i) = o;
}

// ---- QKV GEMM with FUSED epilogues (R7-proven). 128x128 tile, BK=64,
// 4 waves, (256,4). z=0/1: rope+rms via element-aligned bf16 LDS exchange
// between wave pairs (contiguous 64B-line stores; in-wave remap was measured
// to amplify WRITE 38->54MB). z=2: transpose epilogue -> Vt coalesced. ----
__global__ __launch_bounds__(256,4)
void gemm_qkv(const bf16* __restrict__ A, const bf16* __restrict__ Wb,
              bf16* __restrict__ q, bf16* __restrict__ k, bf16* __restrict__ vT,
              const float* __restrict__ cosp, const float* __restrict__ sinp)
{
    __shared__ __align__(16) bf16 smem[17408];   // As | Bs | exchange/ssb
    bf16* As = smem;            // 128*64
    bf16* Bs = smem + 8192;     // 128*64
    const int z = blockIdx.z;
    const bf16* Wm = Wb + (size_t)z*C_*C_;
    const int wave = threadIdx.x >> 6;
    const int lane = threadIdx.x & 63;
    const int l15 = lane & 15, quad = lane >> 4;
    const int row0 = blockIdx.x*128;
    const int col0 = blockIdx.y*128;
    const int wm = (wave>>1)*64, wn = (wave&1)*64;
    const int srow = lane >> 3;
    const int scol = (lane & 7)*8;

    const f32x4 fzero = {0.f,0.f,0.f,0.f};
    f32x4 acc[4][4];
    #pragma unroll
    for (int i=0;i<4;i++)
        #pragma unroll
        for (int j=0;j<4;j++) acc[i][j] = fzero;

    const bf16* Ag = A  + (size_t)(row0 + wave*32 + srow)*C_ + scol;
    const bf16* Bg = Wm + (size_t)(col0 + wave*32 + srow)*C_ + scol;
    bf16* Al = As + (wave*32)*64;
    bf16* Bl = Bs + (wave*32)*64;

    for (int k0 = 0; k0 < C_; k0 += 64) {
        __syncthreads();
        #pragma unroll
        for (int i=0;i<4;i++){
            gl2lds(Ag + (size_t)i*8*C_ + k0, Al + i*8*64);
            gl2lds(Bg + (size_t)i*8*C_ + k0, Bl + i*8*64);
        }
        asm volatile("s_waitcnt vmcnt(0)" ::: "memory");
        __syncthreads();
        #pragma unroll
        for (int h=0; h<2; ++h) {
            short8 af[4], bfv[4];
            #pragma unroll
            for (int mt=0; mt<4; ++mt) af[mt]  = *(const short8*)(As + (wm + mt*16 + l15)*64 + h*32 + quad*8);
            #pragma unroll
            for (int nt=0; nt<4; ++nt) bfv[nt] = *(const short8*)(Bs + (wn + nt*16 + l15)*64 + h*32 + quad*8);
            #pragma unroll
            for (int mt=0; mt<4; ++mt)
                #pragma unroll
                for (int nt=0; nt<4; ++nt)
                    acc[mt][nt] = __builtin_amdgcn_mfma_f32_16x16x32_bf16(af[mt], bfv[nt], acc[mt][nt], 0,0,0);
        }
    }

    __syncthreads();                              // all LDS readers done; reuse smem
    if (z == 2) {
        // ---- transpose epilogue: smem[col][row], RS=136 (16B-aligned rows) ----
        const int RS = 136;
        #pragma unroll
        for (int mt=0; mt<4; ++mt)
            #pragma unroll
            for (int nt=0; nt<4; ++nt) {
                bf4 pk = { f2bf(acc[mt][nt][0]), f2bf(acc[mt][nt][1]),
                           f2bf(acc[mt][nt][2]), f2bf(acc[mt][nt][3]) };
                *(bf4*)(smem + (wn + nt*16 + l15)*RS + wm + mt*16 + quad*4) = pk;
            }
        __syncthreads();
        const int b    = row0 >> 11;              // token row0 / 2048
        const int trow = row0 & 2047;
        const int h    = col0 >> 7;
        bf16* vbase = vT + (size_t)(b*H_ + h)*D_*T_ + trow;
        const int g   = threadIdx.x >> 4;         // 0..15
        const int l16 = threadIdx.x & 15;
        #pragma unroll
        for (int i=0;i<8;i++){
            const int col = i*16 + g;
            *(short8*)(vbase + (size_t)col*T_ + l16*8) = *(const short8*)(smem + col*RS + l16*8);
        }
    } else {
        // ---- rope + rms epilogue (LDS pair exchange) ----
        bf16* dst = z ? k : q;
        bf16* my  = smem + wave*4096;
        bf16* pr  = smem + (wave^1)*4096;
        float* ssb = (float*)(smem + 16384);      // 256 f32
        #pragma unroll
        for (int mt=0; mt<4; ++mt)
            #pragma unroll
            for (int nt=0; nt<4; ++nt) {
                bf4 pk = { f2bf(acc[mt][nt][0]), f2bf(acc[mt][nt][1]),
                           f2bf(acc[mt][nt][2]), f2bf(acc[mt][nt][3]) };
                *(bf4*)(my + ((((mt*4+nt)*4+quad)*16+l15)<<2)) = pk;
            }
        __syncthreads();
        const bool upper = (wave & 1);            // holds d in [64,128)
        float ss[4][4];                            // [mt][r]
        #pragma unroll
        for (int mt=0; mt<4; ++mt) {
            #pragma unroll
            for (int r=0; r<4; ++r) ss[mt][r] = 0.f;
            #pragma unroll
            for (int nt=0; nt<4; ++nt) {
                const bf4 pv = *(const bf4*)(pr + ((((mt*4+nt)*4+quad)*16+l15)<<2));
                const float p[4] = { bf2f(pv.a), bf2f(pv.b), bf2f(pv.c), bf2f(pv.d) };
                const int j = nt*16 + l15;        // head-local half index [0,64)
                #pragma unroll
                for (int r=0; r<4; ++r) {
                    const int t = (row0 + wm + mt*16 + quad*4 + r) & 2047;
                    const float c = cosp[(size_t)t*64 + j];
                    const float s = sinp[(size_t)t*64 + j];
                    // lower: y1 = x1*c + x2*s ; upper: y2 = x2*c - x1*s
                    const float y = upper ? (acc[mt][nt][r]*c - p[r]*s)
                                          : (acc[mt][nt][r]*c + p[r]*s);
                    acc[mt][nt][r] = y;
                    ss[mt][r] += y*y;
                }
            }
            #pragma unroll
            for (int r=0; r<4; ++r) {
                #pragma unroll
                for (int off=1; off<16; off<<=1) ss[mt][r] += __shfl_xor(ss[mt][r], off);
            }
        }
        if (l15 == 0) {
            #pragma unroll
            for (int mt=0; mt<4; ++mt)
                #pragma unroll
                for (int r=0; r<4; ++r)
                    ssb[wave*64 + mt*16 + quad*4 + r] = ss[mt][r];
        }
        __syncthreads();
        #pragma unroll
        for (int mt=0; mt<4; ++mt)
            #pragma unroll
            for (int r=0; r<4; ++r) {
                const float sst = ss[mt][r] + ssb[(wave^1)*64 + mt*16 + quad*4 + r];
                const float sc = rsqrtf(sst*(1.0f/128.0f) + 1e-5f);
                #pragma unroll
                for (int nt=0; nt<4; ++nt)
                    dst[(size_t)(row0 + wm + mt*16 + quad*4 + r)*C_ + col0 + wn + nt*16 + l15]
                        = f2bf(acc[mt][nt][r]*sc);
            }
    }
}

// ---- proj GEMM, 64x128 tiles: 640 blocks fill the machine in one round ----
__global__ __launch_bounds__(256,4)
void gemm_nt_m64(const bf16* __restrict__ A, const bf16* __restrict__ Wm,
                 float* __restrict__ Om)
{
    __shared__ __align__(16) bf16 As[64*64];
    __shared__ __align__(16) bf16 Bs[128*64];
    const int wave = threadIdx.x >> 6;
    const int lane = threadIdx.x & 63;
    const int l15 = lane & 15, quad = lane >> 4;
    const int row0 = blockIdx.x*64;
    const int col0 = blockIdx.y*128;
    const int wm = (wave>>1)*32, wn = (wave&1)*64;
    const int srow = lane >> 3;
    const int scol = (lane & 7)*8;

    const f32x4 fzero = {0.f,0.f,0.f,0.f};
    f32x4 acc[2][4];
    #pragma unroll
    for (int i=0;i<2;i++)
        #pragma unroll
        for (int j=0;j<4;j++) acc[i][j] = fzero;

    const bf16* Ag = A  + (size_t)(row0 + wave*16 + srow)*C_ + scol;
    const bf16* Bg = Wm + (size_t)(col0 + wave*32 + srow)*C_ + scol;
    bf16* Al = As + (wave*16)*64;
    bf16* Bl = Bs + (wave*32)*64;

    for (int k0 = 0; k0 < C_; k0 += 64) {
        __syncthreads();
        #pragma unroll
        for (int i=0;i<2;i++)
            gl2lds(Ag + (size_t)i*8*C_ + k0, Al + i*8*64);
        #pragma unroll
        for (int i=0;i<4;i++)
            gl2lds(Bg + (size_t)i*8*C_ + k0, Bl + i*8*64);
        asm volatile("s_waitcnt vmcnt(0)" ::: "memory");
        __syncthreads();
        #pragma unroll
        for (int h=0; h<2; ++h) {
            short8 af[2], bfv[4];
            #pragma unroll
            for (int mt=0; mt<2; ++mt) af[mt]  = *(const short8*)(As + (wm + mt*16 + l15)*64 + h*32 + quad*8);
            #pragma unroll
            for (int nt=0; nt<4; ++nt) bfv[nt] = *(const short8*)(Bs + (wn + nt*16 + l15)*64 + h*32 + quad*8);
            #pragma unroll
            for (int mt=0; mt<2; ++mt)
                #pragma unroll
                for (int nt=0; nt<4; ++nt)
                    acc[mt][nt] = __builtin_amdgcn_mfma_f32_16x16x32_bf16(af[mt], bfv[nt], acc[mt][nt], 0,0,0);
        }
    }
    #pragma unroll
    for (int mt=0; mt<2; ++mt)
        #pragma unroll
        for (int nt=0; nt<4; ++nt)
            #pragma unroll
            for (int r=0; r<4; ++r)
                Om[(size_t)(row0 + wm + mt*16 + quad*4 + r)*C_ + col0 + wn + nt*16 + l15] = acc[mt][nt][r];
}

// ---- Flash attention v14: v12's proven inner loop + key-axis segmentation
// (<=8-chunk segments, 1600 blocks), with combineN FUSED via split-K
// last-arriver tickets: each partial block drains stores (__syncthreads),
// __threadfence (agent wbL2), atomicAdd ticket; the last segment block
// re-fences (L2 inv) and combines+writes Y in place. Saves the combineN
// launch + its boundary; combine work overlaps still-running blocks. ----
#define M0_ 11.3137085f
__global__ __launch_bounds__(256,3)
void attn(const bf16* __restrict__ Q, const bf16* __restrict__ K,
          const bf16* __restrict__ Vt, bf16* __restrict__ Y,
          bf16* __restrict__ opart, float* __restrict__ lpart,
          int* __restrict__ cnt)
{
    __shared__ __align__(16) bf16 kbuf[64*128];      // [key][16B-unit, rot16], 16 KB
    __shared__ __align__(16) bf16 vbuf[128*64];      // [d][16B-unit, rot8], 16 KB
    __shared__ __align__(16) bf16 ptile[4][16*72];   // per-wave P tile
    __shared__ int comb_old;
    const int wave = threadIdx.x >> 6, lane = threadIdx.x & 63;
    const int l15 = lane & 15, quad = lane >> 4;
    const int bh = blockIdx.x % 20;
    const int u  = blockIdx.x / 20;                  // 0..79, heavy segments first
    int m, seg;
    if (u < 32)      { m = 31 - (u>>2); seg = u & 3; }
    else if (u < 56) { const int v2 = u-32; m = 23 - v2/3; seg = v2%3; }
    else if (u < 72) { const int v2 = u-56; m = 15 - (v2>>1); seg = v2&1; }
    else             { m = 7 - (u-72); seg = 0; }
    const int b = bh / H_, h = bh % H_;
    const int t0 = m*64;
    const int nch = m + 1;                           // 64-key chunks in tile
    const int cbeg = seg*8;
    const int cend = min(cbeg+8, nch);
    const bool direct = (m < 8);                     // single-segment tile
    const size_t base = (size_t)b*T_*C_ + (size_t)h*D_;
    const bf16* Kbh = K + base;
    const bf16* Vbh = Vt + (size_t)bh*D_*T_;
    const int t0w = t0 + wave*16;
    const float scale = 0.08838834764831845f;        // 1/sqrt(128)
    bf16* pt = ptile[wave];

    short8 qa[4];
    {
        const bf16* qp = Q + base + (size_t)(t0w + l15)*C_ + quad*8;
        #pragma unroll
        for (int kb4=0; kb4<4; ++kb4) qa[kb4] = *(const short8*)(qp + kb4*32);
    }
    const f32x4 fzero = {0.f,0.f,0.f,0.f};
    f32x4 o[8];
    #pragma unroll
    for (int dt=0; dt<8; ++dt) o[dt] = fzero;
    float lp[4] = {0.f,0.f,0.f,0.f};

    // V DMA lane mapping (row stride 128 B = 8 units of 16 B)
    const int vr_off = lane >> 3;                // 0..7 within an 8-row group
    const int vu     = lane & 7;

    for (int ch=cbeg; ch<cend; ++ch) {
        const int k0 = ch*64;
        __syncthreads();                          // prev chunk's readers done
        // --- DMA K: wave stages key rows [16w,16w+16), rot-16 swizzle ---
        #pragma unroll
        for (int j=0;j<4;j++){
            const int row = wave*16 + j*4 + quad;
            const int ugk = (l15 - row) & 15;
            gl2lds(Kbh + (size_t)(k0 + row)*C_ + ugk*8, &kbuf[(wave*16 + j*4)*128]);
        }
        // --- DMA V: wave stages d rows [32w,32w+32), rot-8 swizzle ---
        #pragma unroll
        for (int j=0;j<4;j++){
            const int r  = wave*32 + j*8 + vr_off;
            const int ugv = (vu - r) & 7;
            gl2lds(Vbh + (size_t)r*T_ + k0 + ugv*8, &vbuf[(wave*32 + j*8)*64]);
        }
        asm volatile("s_waitcnt vmcnt(0)" ::: "memory");
        __syncthreads();                          // staged chunk visible

        // --- QK from LDS K ---
        f32x4 sc4[4];
        #pragma unroll
        for (int c=0;c<4;c++) sc4[c] = fzero;
        #pragma unroll
        for (int c=0;c<4;c++){
            short8 kf[4];
            #pragma unroll
            for (int kb4=0; kb4<4; ++kb4) {
                const int up = (kb4*4 + quad + l15) & 15;
                kf[kb4] = *(const short8*)(&kbuf[(c*16 + l15)*128 + up*8]);
            }
            #pragma unroll
            for (int kb4=0; kb4<4; ++kb4)
                sc4[c] = __builtin_amdgcn_mfma_f32_16x16x32_bf16(qa[kb4], kf[kb4], sc4[c], 0,0,0);
        }
        // --- softmax (fixed max) + P to LDS ---
        const bool lastc = (ch == nch-1);
        #pragma unroll
        for (int r=0; r<4; ++r) {
            const int rt = t0w + quad*4 + r;
            float v[4];
            #pragma unroll
            for (int c=0;c<4;c++) v[c] = sc4[c][r]*scale;
            if (lastc) {
                #pragma unroll
                for (int c=0;c<4;c++) if (k0 + c*16 + l15 > rt) v[c] = -1e30f;
            }
            float p[4];
            #pragma unroll
            for (int c=0;c<4;c++) p[c] = __expf(v[c] - M0_);
            lp[r] += (p[0]+p[1]) + (p[2]+p[3]);
            #pragma unroll
            for (int c=0;c<4;c++) pt[(quad*4+r)*72 + c*16 + l15] = f2bf(p[c]);
        }
        asm volatile("s_waitcnt lgkmcnt(0)" ::: "memory");   // own wave's P writes visible
        short8 pa[2];
        #pragma unroll
        for (int ks=0; ks<2; ++ks)
            pa[ks] = *(const short8*)(pt + l15*72 + ks*32 + quad*8);
        // --- PV from LDS V ---
        #pragma unroll
        for (int dt=0; dt<8; ++dt) {
            #pragma unroll
            for (int ks=0; ks<2; ++ks) {
                const int up = (ks*4 + quad + l15) & 7;
                short8 vF = *(const short8*)(&vbuf[(dt*16 + l15)*64 + up*8]);
                o[dt] = __builtin_amdgcn_mfma_f32_16x16x32_bf16(pa[ks], vF, o[dt], 0,0,0);
            }
        }
    }

    // l reduction over the 16-lane row group
    #pragma unroll
    for (int r=0; r<4; ++r) {
        #pragma unroll
        for (int off=1; off<16; off<<=1) lp[r] += __shfl_xor(lp[r], off);
    }
    if (direct) {
        float li[4];
        #pragma unroll
        for (int r=0; r<4; ++r) li[r] = 1.0f/lp[r];
        #pragma unroll
        for (int dt=0; dt<8; ++dt)
            #pragma unroll
            for (int r=0; r<4; ++r)
                Y[base + (size_t)(t0w + quad*4 + r)*C_ + dt*16 + l15] = f2bf(o[dt][r]*li[r]);
    } else {
        // packed slot: per-bh 72 partial segments (tiles m>=8)
        const int off = (m<16) ? (m-8)*2 : (m<24) ? 16 + (m-16)*3 : 40 + (m-24)*4;
        const int slot = bh*72 + off + seg;
        bf16* ob = opart + (size_t)slot*8192 + (wave*16)*128;
        #pragma unroll
        for (int dt=0; dt<8; ++dt)
            #pragma unroll
            for (int r=0; r<4; ++r)
                ob[(quad*4+r)*128 + dt*16 + l15] = f2bf(o[dt][r]);
        if (l15 == 0) {
            #pragma unroll
            for (int r=0; r<4; ++r) lpart[(size_t)slot*64 + wave*16 + quad*4 + r] = lp[r];
        }
        // ---- fused combine: last-arriving segment block of this tile ----
        const int nseg = (m + 8) >> 3;           // 2..4
        __syncthreads();                          // all waves' stores drained (vmcnt0 before barrier)
        if (threadIdx.x == 0) {
            __threadfence();                      // agent-scope release (wbL2)
            comb_old = atomicAdd(&cnt[bh*24 + (m-8)], 1);
        }
        __syncthreads();
        if (comb_old == nseg-1) {
            __threadfence();                      // agent-scope acquire (invL2)
            const int slot0 = bh*72 + off;
            const int row = threadIdx.x >> 2;     // 0..63
            const int d0c = (threadIdx.x & 3)*32;
            float l = 0.f;
            for (int s2=0; s2<nseg; ++s2) l += lpart[(size_t)(slot0+s2)*64 + row];
            const float li = 1.0f/l;
            float accc[32];
            #pragma unroll
            for (int e=0;e<32;e++) accc[e] = 0.f;
            for (int s2=0; s2<nseg; ++s2) {
                const bf16* p = opart + (size_t)(slot0+s2)*8192 + row*128 + d0c;
                #pragma unroll
                for (int e=0;e<32;e++) accc[e] += bf2f(p[e]);
            }
            bf16 ov[32];
            #pragma unroll
            for (int e=0;e<32;e++) ov[e] = f2bf(accc[e]*li);
            bf16* yp = Y + (size_t)b*T_*C_ + (size_t)(m*64+row)*C_ + (size_t)h*D_ + d0c;
            #pragma unroll
            for (int v=0; v<4; ++v) *(short8*)(yp + v*8) = *(const short8*)(&ov[v*8]);
        }
    }
}

extern "C" void kernel_launch(void* const* d_in, const int* in_sizes, int n_in,
                              void* d_out, int out_size, void* d_ws, size_t ws_size,
                              hipStream_t stream)
{
    const float* x    = (const float*)d_in[0];
    const float* cosp = (const float*)d_in[1];
    const float* sinp = (const float*)d_in[2];
    const float* Wq   = (const float*)d_in[3];
    const float* Wk   = (const float*)d_in[4];
    const float* Wv   = (const float*)d_in[5];
    const float* Wp   = (const float*)d_in[6];
    float* out = (float*)d_out;

    const size_t NE = (size_t)BT_ * C_;
    const size_t NW = (size_t)C_ * C_;
    bf16* xb = (bf16*)d_ws;
    bf16* wb = xb + NE;
    bf16* q  = wb + 4*NW;
    bf16* k  = q + NE;
    bf16* y  = k + NE;
    bf16* vT = y + NE;
    bf16* op = vT + NE;                               // 1440 slots x 8192 bf16 (23.6 MB)
    float* lpart = (float*)(op + (size_t)1440*8192);  // 1440 x 64 f32
    int*   cnt   = (int*)(lpart + (size_t)1440*64);   // 480 tickets

    cvtall<<<dim3(11520), 256, 0, stream>>>(x, Wq, Wk, Wv, Wp, xb, wb, cnt);
    gemm_qkv<<<dim3(BT_/128, C_/128, 3), 256, 0, stream>>>(xb, wb, q, k, vT, cosp, sinp);
    attn<<<dim3(1600), 256, 0, stream>>>(q, k, vT, y, op, lpart, cnt);
    gemm_nt_m64<<<dim3(BT_/64, C_/128), 256, 0, stream>>>(y, wb + 3*NW, out);
}

// Round 11
// 231.958 us; speedup vs baseline: 1.8154x; 1.8154x over previous
//
#include <hip/hip_runtime.h>
#include <hip/hip_bf16.h>

#define B_ 2
#define T_ 2048
#define C_ 1280
#define H_ 10
#define D_ 128
#define BT_ (B_*T_)

typedef __hip_bfloat16 bf16;
typedef __attribute__((ext_vector_type(8))) short short8;
typedef __attribute__((ext_vector_type(4))) float f32x4;

__device__ __forceinline__ float bf2f(bf16 v){ return __bfloat162float(v); }
__device__ __forceinline__ bf16  f2bf(float v){ return __float2bfloat16(v); }

struct alignas(8) bf4 { bf16 a,b,c,d; };

__device__ __forceinline__ void gl2lds(const bf16* g, bf16* l) {
    __builtin_amdgcn_global_load_lds(
        (const __attribute__((address_space(1))) void*)g,
        (__attribute__((address_space(3))) void*)l,
        16, 0, 0);
}

// ---- fused fp32->bf16 convert: x (5120 blocks) + 4 weight mats (1600 each) ----
__global__ __launch_bounds__(256)
void cvtall(const float* __restrict__ x,  const float* __restrict__ w0,
            const float* __restrict__ w1, const float* __restrict__ w2,
            const float* __restrict__ w3, bf16* __restrict__ xb,
            bf16* __restrict__ wb)
{
    int bid = blockIdx.x;
    const float* s; bf16* d; int i;
    if (bid < 5120) {
        s = x; d = xb; i = (bid*256 + threadIdx.x)*4;
    } else {
        bid -= 5120;
        const int w = bid / 1600;
        const int r = bid % 1600;
        s = (w==0)?w0:(w==1)?w1:(w==2)?w2:w3;
        d = wb + (size_t)w*C_*C_;
        i = (r*256 + threadIdx.x)*4;
    }
    const float4 v = *(const float4*)(s + i);
    bf4 o = { f2bf(v.x), f2bf(v.y), f2bf(v.z), f2bf(v.w) };
    *(bf4*)(d + i) = o;
}

// ---- QKV GEMM with FUSED epilogues (R7-proven best). 128x128 tile, BK=64,
// 4 waves, (256,4). z=0/1 (q,k): rope+rms fused -- wave pairs (0,1)/(2,3)
// hold the d<64/d>=64 halves of the same 64 rows; element-aligned bf16 LDS
// exchange, per-row sum via 16-lane shuffle + small LDS exchange, scale,
// store (contiguous 64B-line stores; in-wave col remap was measured to
// amplify WRITE 38->54MB -- do not reintroduce).
// z=2 (v): transpose fused -- acc written transposed to padded LDS (RS=136
// keeps b128 reads 16B-aligned), rows read contiguously, Vt coalesced. ----
__global__ __launch_bounds__(256,4)
void gemm_qkv(const bf16* __restrict__ A, const bf16* __restrict__ Wb,
              bf16* __restrict__ q, bf16* __restrict__ k, bf16* __restrict__ vT,
              const float* __restrict__ cosp, const float* __restrict__ sinp)
{
    __shared__ __align__(16) bf16 smem[17408];   // As | Bs | exchange/ssb
    bf16* As = smem;            // 128*64
    bf16* Bs = smem + 8192;     // 128*64
    const int z = blockIdx.z;
    const bf16* Wm = Wb + (size_t)z*C_*C_;
    const int wave = threadIdx.x >> 6;
    const int lane = threadIdx.x & 63;
    const int l15 = lane & 15, quad = lane >> 4;
    const int row0 = blockIdx.x*128;
    const int col0 = blockIdx.y*128;
    const int wm = (wave>>1)*64, wn = (wave&1)*64;
    const int srow = lane >> 3;
    const int scol = (lane & 7)*8;

    const f32x4 fzero = {0.f,0.f,0.f,0.f};
    f32x4 acc[4][4];
    #pragma unroll
    for (int i=0;i<4;i++)
        #pragma unroll
        for (int j=0;j<4;j++) acc[i][j] = fzero;

    const bf16* Ag = A  + (size_t)(row0 + wave*32 + srow)*C_ + scol;
    const bf16* Bg = Wm + (size_t)(col0 + wave*32 + srow)*C_ + scol;
    bf16* Al = As + (wave*32)*64;
    bf16* Bl = Bs + (wave*32)*64;

    for (int k0 = 0; k0 < C_; k0 += 64) {
        __syncthreads();
        #pragma unroll
        for (int i=0;i<4;i++){
            gl2lds(Ag + (size_t)i*8*C_ + k0, Al + i*8*64);
            gl2lds(Bg + (size_t)i*8*C_ + k0, Bl + i*8*64);
        }
        asm volatile("s_waitcnt vmcnt(0)" ::: "memory");
        __syncthreads();
        #pragma unroll
        for (int h=0; h<2; ++h) {
            short8 af[4], bfv[4];
            #pragma unroll
            for (int mt=0; mt<4; ++mt) af[mt]  = *(const short8*)(As + (wm + mt*16 + l15)*64 + h*32 + quad*8);
            #pragma unroll
            for (int nt=0; nt<4; ++nt) bfv[nt] = *(const short8*)(Bs + (wn + nt*16 + l15)*64 + h*32 + quad*8);
            #pragma unroll
            for (int mt=0; mt<4; ++mt)
                #pragma unroll
                for (int nt=0; nt<4; ++nt)
                    acc[mt][nt] = __builtin_amdgcn_mfma_f32_16x16x32_bf16(af[mt], bfv[nt], acc[mt][nt], 0,0,0);
        }
    }

    __syncthreads();                              // all LDS readers done; reuse smem
    if (z == 2) {
        // ---- transpose epilogue: smem[col][row], RS=136 (16B-aligned rows) ----
        const int RS = 136;
        #pragma unroll
        for (int mt=0; mt<4; ++mt)
            #pragma unroll
            for (int nt=0; nt<4; ++nt) {
                bf4 pk = { f2bf(acc[mt][nt][0]), f2bf(acc[mt][nt][1]),
                           f2bf(acc[mt][nt][2]), f2bf(acc[mt][nt][3]) };
                *(bf4*)(smem + (wn + nt*16 + l15)*RS + wm + mt*16 + quad*4) = pk;
            }
        __syncthreads();
        const int b    = row0 >> 11;              // token row0 / 2048
        const int trow = row0 & 2047;
        const int h    = col0 >> 7;
        bf16* vbase = vT + (size_t)(b*H_ + h)*D_*T_ + trow;
        const int g   = threadIdx.x >> 4;         // 0..15
        const int l16 = threadIdx.x & 15;
        #pragma unroll
        for (int i=0;i<8;i++){
            const int col = i*16 + g;
            *(short8*)(vbase + (size_t)col*T_ + l16*8) = *(const short8*)(smem + col*RS + l16*8);
        }
    } else {
        // ---- rope + rms epilogue (LDS pair exchange) ----
        bf16* dst = z ? k : q;
        bf16* my  = smem + wave*4096;
        bf16* pr  = smem + (wave^1)*4096;
        float* ssb = (float*)(smem + 16384);      // 256 f32
        // write own fragments (element-aligned layout, b64 per (mt,nt))
        #pragma unroll
        for (int mt=0; mt<4; ++mt)
            #pragma unroll
            for (int nt=0; nt<4; ++nt) {
                bf4 pk = { f2bf(acc[mt][nt][0]), f2bf(acc[mt][nt][1]),
                           f2bf(acc[mt][nt][2]), f2bf(acc[mt][nt][3]) };
                *(bf4*)(my + ((((mt*4+nt)*4+quad)*16+l15)<<2)) = pk;
            }
        __syncthreads();
        const bool upper = (wave & 1);            // holds d in [64,128)
        float ss[4][4];                            // [mt][r]
        #pragma unroll
        for (int mt=0; mt<4; ++mt) {
            #pragma unroll
            for (int r=0; r<4; ++r) ss[mt][r] = 0.f;
            #pragma unroll
            for (int nt=0; nt<4; ++nt) {
                const bf4 pv = *(const bf4*)(pr + ((((mt*4+nt)*4+quad)*16+l15)<<2));
                const float p[4] = { bf2f(pv.a), bf2f(pv.b), bf2f(pv.c), bf2f(pv.d) };
                const int j = nt*16 + l15;        // head-local half index [0,64)
                #pragma unroll
                for (int r=0; r<4; ++r) {
                    const int t = (row0 + wm + mt*16 + quad*4 + r) & 2047;
                    const float c = cosp[(size_t)t*64 + j];
                    const float s = sinp[(size_t)t*64 + j];
                    // lower: y1 = x1*c + x2*s ; upper: y2 = x2*c - x1*s
                    const float y = upper ? (acc[mt][nt][r]*c - p[r]*s)
                                          : (acc[mt][nt][r]*c + p[r]*s);
                    acc[mt][nt][r] = y;
                    ss[mt][r] += y*y;
                }
            }
            #pragma unroll
            for (int r=0; r<4; ++r) {
                #pragma unroll
                for (int off=1; off<16; off<<=1) ss[mt][r] += __shfl_xor(ss[mt][r], off);
            }
        }
        if (l15 == 0) {
            #pragma unroll
            for (int mt=0; mt<4; ++mt)
                #pragma unroll
                for (int r=0; r<4; ++r)
                    ssb[wave*64 + mt*16 + quad*4 + r] = ss[mt][r];
        }
        __syncthreads();
        #pragma unroll
        for (int mt=0; mt<4; ++mt)
            #pragma unroll
            for (int r=0; r<4; ++r) {
                const float sst = ss[mt][r] + ssb[(wave^1)*64 + mt*16 + quad*4 + r];
                const float sc = rsqrtf(sst*(1.0f/128.0f) + 1e-5f);
                #pragma unroll
                for (int nt=0; nt<4; ++nt)
                    dst[(size_t)(row0 + wm + mt*16 + quad*4 + r)*C_ + col0 + wn + nt*16 + l15]
                        = f2bf(acc[mt][nt][r]*sc);
            }
    }
}

// ---- proj GEMM, 64x128 tiles: 640 blocks fill the machine in one round ----
__global__ __launch_bounds__(256,4)
void gemm_nt_m64(const bf16* __restrict__ A, const bf16* __restrict__ Wm,
                 float* __restrict__ Om)
{
    __shared__ __align__(16) bf16 As[64*64];
    __shared__ __align__(16) bf16 Bs[128*64];
    const int wave = threadIdx.x >> 6;
    const int lane = threadIdx.x & 63;
    const int l15 = lane & 15, quad = lane >> 4;
    const int row0 = blockIdx.x*64;
    const int col0 = blockIdx.y*128;
    const int wm = (wave>>1)*32, wn = (wave&1)*64;
    const int srow = lane >> 3;
    const int scol = (lane & 7)*8;

    const f32x4 fzero = {0.f,0.f,0.f,0.f};
    f32x4 acc[2][4];
    #pragma unroll
    for (int i=0;i<2;i++)
        #pragma unroll
        for (int j=0;j<4;j++) acc[i][j] = fzero;

    const bf16* Ag = A  + (size_t)(row0 + wave*16 + srow)*C_ + scol;
    const bf16* Bg = Wm + (size_t)(col0 + wave*32 + srow)*C_ + scol;
    bf16* Al = As + (wave*16)*64;
    bf16* Bl = Bs + (wave*32)*64;

    for (int k0 = 0; k0 < C_; k0 += 64) {
        __syncthreads();
        #pragma unroll
        for (int i=0;i<2;i++)
            gl2lds(Ag + (size_t)i*8*C_ + k0, Al + i*8*64);
        #pragma unroll
        for (int i=0;i<4;i++)
            gl2lds(Bg + (size_t)i*8*C_ + k0, Bl + i*8*64);
        asm volatile("s_waitcnt vmcnt(0)" ::: "memory");
        __syncthreads();
        #pragma unroll
        for (int h=0; h<2; ++h) {
            short8 af[2], bfv[4];
            #pragma unroll
            for (int mt=0; mt<2; ++mt) af[mt]  = *(const short8*)(As + (wm + mt*16 + l15)*64 + h*32 + quad*8);
            #pragma unroll
            for (int nt=0; nt<4; ++nt) bfv[nt] = *(const short8*)(Bs + (wn + nt*16 + l15)*64 + h*32 + quad*8);
            #pragma unroll
            for (int mt=0; mt<2; ++mt)
                #pragma unroll
                for (int nt=0; nt<4; ++nt)
                    acc[mt][nt] = __builtin_amdgcn_mfma_f32_16x16x32_bf16(af[mt], bfv[nt], acc[mt][nt], 0,0,0);
        }
    }
    #pragma unroll
    for (int mt=0; mt<2; ++mt)
        #pragma unroll
        for (int nt=0; nt<4; ++nt)
            #pragma unroll
            for (int r=0; r<4; ++r)
                Om[(size_t)(row0 + wm + mt*16 + quad*4 + r)*C_ + col0 + wn + nt*16 + l15] = acc[mt][nt][r];
}

// ---- Flash attention v12 (PROVEN BEST): 64-row q-tile, 4 waves x 16 rows,
// single-buffered K/V LDS staging, rot swizzles, fixed softmax max, key-axis
// segmented decomposition (segments of <=8 chunks -> 1600 near-uniform
// blocks, 6400 waves). Multi-segment tiles write unscaled bf16 partials +
// row-l; combineN normalizes. [R8: 128-row/4-chunk explodes partial HBM
// traffic. R10: fence-fused combine costs ~100us-scale L2 writebacks --
// keep combineN a separate launch.] ----
#define M0_ 11.3137085f
__global__ __launch_bounds__(256,3)
void attn(const bf16* __restrict__ Q, const bf16* __restrict__ K,
          const bf16* __restrict__ Vt, bf16* __restrict__ Y,
          bf16* __restrict__ opart, float* __restrict__ lpart)
{
    __shared__ __align__(16) bf16 kbuf[64*128];      // [key][16B-unit, rot16], 16 KB
    __shared__ __align__(16) bf16 vbuf[128*64];      // [d][16B-unit, rot8], 16 KB
    __shared__ __align__(16) bf16 ptile[4][16*72];   // per-wave P tile
    const int wave = threadIdx.x >> 6, lane = threadIdx.x & 63;
    const int l15 = lane & 15, quad = lane >> 4;
    const int bh = blockIdx.x % 20;
    const int u  = blockIdx.x / 20;                  // 0..79, heavy segments first
    int m, seg;
    if (u < 32)      { m = 31 - (u>>2); seg = u & 3; }
    else if (u < 56) { const int v2 = u-32; m = 23 - v2/3; seg = v2%3; }
    else if (u < 72) { const int v2 = u-56; m = 15 - (v2>>1); seg = v2&1; }
    else             { m = 7 - (u-72); seg = 0; }
    const int b = bh / H_, h = bh % H_;
    const int t0 = m*64;
    const int nch = m + 1;                           // 64-key chunks in tile
    const int cbeg = seg*8;
    const int cend = min(cbeg+8, nch);
    const bool direct = (m < 8);                     // single-segment tile
    const size_t base = (size_t)b*T_*C_ + (size_t)h*D_;
    const bf16* Kbh = K + base;
    const bf16* Vbh = Vt + (size_t)bh*D_*T_;
    const int t0w = t0 + wave*16;
    const float scale = 0.08838834764831845f;        // 1/sqrt(128)
    bf16* pt = ptile[wave];

    short8 qa[4];
    {
        const bf16* qp = Q + base + (size_t)(t0w + l15)*C_ + quad*8;
        #pragma unroll
        for (int kb4=0; kb4<4; ++kb4) qa[kb4] = *(const short8*)(qp + kb4*32);
    }
    const f32x4 fzero = {0.f,0.f,0.f,0.f};
    f32x4 o[8];
    #pragma unroll
    for (int dt=0; dt<8; ++dt) o[dt] = fzero;
    float lp[4] = {0.f,0.f,0.f,0.f};

    // V DMA lane mapping (row stride 128 B = 8 units of 16 B)
    const int vr_off = lane >> 3;                // 0..7 within an 8-row group
    const int vu     = lane & 7;

    for (int ch=cbeg; ch<cend; ++ch) {
        const int k0 = ch*64;
        __syncthreads();                          // prev chunk's readers done
        // --- DMA K: wave stages key rows [16w,16w+16), rot-16 swizzle ---
        #pragma unroll
        for (int j=0;j<4;j++){
            const int row = wave*16 + j*4 + quad;
            const int ugk = (l15 - row) & 15;
            gl2lds(Kbh + (size_t)(k0 + row)*C_ + ugk*8, &kbuf[(wave*16 + j*4)*128]);
        }
        // --- DMA V: wave stages d rows [32w,32w+32), rot-8 swizzle ---
        #pragma unroll
        for (int j=0;j<4;j++){
            const int r  = wave*32 + j*8 + vr_off;
            const int ugv = (vu - r) & 7;
            gl2lds(Vbh + (size_t)r*T_ + k0 + ugv*8, &vbuf[(wave*32 + j*8)*64]);
        }
        asm volatile("s_waitcnt vmcnt(0)" ::: "memory");
        __syncthreads();                          // staged chunk visible

        // --- QK from LDS K ---
        f32x4 sc4[4];
        #pragma unroll
        for (int c=0;c<4;c++) sc4[c] = fzero;
        #pragma unroll
        for (int c=0;c<4;c++){
            short8 kf[4];
            #pragma unroll
            for (int kb4=0; kb4<4; ++kb4) {
                const int up = (kb4*4 + quad + l15) & 15;
                kf[kb4] = *(const short8*)(&kbuf[(c*16 + l15)*128 + up*8]);
            }
            #pragma unroll
            for (int kb4=0; kb4<4; ++kb4)
                sc4[c] = __builtin_amdgcn_mfma_f32_16x16x32_bf16(qa[kb4], kf[kb4], sc4[c], 0,0,0);
        }
        // --- softmax (fixed max) + P to LDS ---
        const bool lastc = (ch == nch-1);
        #pragma unroll
        for (int r=0; r<4; ++r) {
            const int rt = t0w + quad*4 + r;
            float v[4];
            #pragma unroll
            for (int c=0;c<4;c++) v[c] = sc4[c][r]*scale;
            if (lastc) {
                #pragma unroll
                for (int c=0;c<4;c++) if (k0 + c*16 + l15 > rt) v[c] = -1e30f;
            }
            float p[4];
            #pragma unroll
            for (int c=0;c<4;c++) p[c] = __expf(v[c] - M0_);
            lp[r] += (p[0]+p[1]) + (p[2]+p[3]);
            #pragma unroll
            for (int c=0;c<4;c++) pt[(quad*4+r)*72 + c*16 + l15] = f2bf(p[c]);
        }
        asm volatile("s_waitcnt lgkmcnt(0)" ::: "memory");   // own wave's P writes visible
        short8 pa[2];
        #pragma unroll
        for (int ks=0; ks<2; ++ks)
            pa[ks] = *(const short8*)(pt + l15*72 + ks*32 + quad*8);
        // --- PV from LDS V ---
        #pragma unroll
        for (int dt=0; dt<8; ++dt) {
            #pragma unroll
            for (int ks=0; ks<2; ++ks) {
                const int up = (ks*4 + quad + l15) & 7;
                short8 vF = *(const short8*)(&vbuf[(dt*16 + l15)*64 + up*8]);
                o[dt] = __builtin_amdgcn_mfma_f32_16x16x32_bf16(pa[ks], vF, o[dt], 0,0,0);
            }
        }
    }

    // l reduction over the 16-lane row group
    #pragma unroll
    for (int r=0; r<4; ++r) {
        #pragma unroll
        for (int off=1; off<16; off<<=1) lp[r] += __shfl_xor(lp[r], off);
    }
    if (direct) {
        float li[4];
        #pragma unroll
        for (int r=0; r<4; ++r) li[r] = 1.0f/lp[r];
        #pragma unroll
        for (int dt=0; dt<8; ++dt)
            #pragma unroll
            for (int r=0; r<4; ++r)
                Y[base + (size_t)(t0w + quad*4 + r)*C_ + dt*16 + l15] = f2bf(o[dt][r]*li[r]);
    } else {
        // packed slot: per-bh 72 partial segments (tiles m>=8)
        const int off = (m<16) ? (m-8)*2 : (m<24) ? 16 + (m-16)*3 : 40 + (m-24)*4;
        const int slot = bh*72 + off + seg;
        bf16* ob = opart + (size_t)slot*8192 + (wave*16)*128;
        #pragma unroll
        for (int dt=0; dt<8; ++dt)
            #pragma unroll
            for (int r=0; r<4; ++r)
                ob[(quad*4+r)*128 + dt*16 + l15] = f2bf(o[dt][r]);
        if (l15 == 0) {
            #pragma unroll
            for (int r=0; r<4; ++r) lpart[(size_t)slot*64 + wave*16 + quad*4 + r] = lp[r];
        }
    }
}

// ---- combine 2..4 key-segment partials for tiles m in [8,32) ----
__global__ __launch_bounds__(256)
void combineN(const bf16* __restrict__ opart, const float* __restrict__ lpart,
              bf16* __restrict__ Y)
{
    const int tt = blockIdx.x;            // 0..479: bh*24 + (m-8)
    const int bh = tt / 24;
    const int m  = 8 + (tt % 24);
    const int nseg = (m + 8) >> 3;        // ceil((m+1)/8): 2..4
    const int off = (m<16) ? (m-8)*2 : (m<24) ? 16 + (m-16)*3 : 40 + (m-24)*4;
    const int slot0 = bh*72 + off;
    const int b = bh / H_, h = bh % H_;
    const int row = threadIdx.x >> 2;     // 0..63
    const int d0 = (threadIdx.x & 3)*32;
    float l = 0.f;
    for (int s=0; s<nseg; ++s) l += lpart[(size_t)(slot0+s)*64 + row];
    const float li = 1.0f/l;
    float acc[32];
    #pragma unroll
    for (int e=0;e<32;e++) acc[e] = 0.f;
    for (int s=0; s<nseg; ++s) {
        const bf16* p = opart + (size_t)(slot0+s)*8192 + row*128 + d0;
        #pragma unroll
        for (int e=0;e<32;e++) acc[e] += bf2f(p[e]);
    }
    bf16 ov[32];
    #pragma unroll
    for (int e=0;e<32;e++) ov[e] = f2bf(acc[e]*li);
    bf16* yp = Y + (size_t)b*T_*C_ + (size_t)(m*64+row)*C_ + (size_t)h*D_ + d0;
    #pragma unroll
    for (int v=0; v<4; ++v) *(short8*)(yp + v*8) = *(const short8*)(&ov[v*8]);
}

extern "C" void kernel_launch(void* const* d_in, const int* in_sizes, int n_in,
                              void* d_out, int out_size, void* d_ws, size_t ws_size,
                              hipStream_t stream)
{
    const float* x    = (const float*)d_in[0];
    const float* cosp = (const float*)d_in[1];
    const float* sinp = (const float*)d_in[2];
    const float* Wq   = (const float*)d_in[3];
    const float* Wk   = (const float*)d_in[4];
    const float* Wv   = (const float*)d_in[5];
    const float* Wp   = (const float*)d_in[6];
    float* out = (float*)d_out;

    const size_t NE = (size_t)BT_ * C_;
    const size_t NW = (size_t)C_ * C_;
    bf16* xb = (bf16*)d_ws;
    bf16* wb = xb + NE;
    bf16* q  = wb + 4*NW;
    bf16* k  = q + NE;
    bf16* y  = k + NE;
    bf16* vT = y + NE;
    bf16* op = vT + NE;                               // 1440 slots x 8192 bf16 (23.6 MB)
    float* lpart = (float*)(op + (size_t)1440*8192);  // 1440 x 64 f32

    cvtall<<<dim3(11520), 256, 0, stream>>>(x, Wq, Wk, Wv, Wp, xb, wb);
    gemm_qkv<<<dim3(BT_/128, C_/128, 3), 256, 0, stream>>>(xb, wb, q, k, vT, cosp, sinp);
    attn<<<dim3(1600), 256, 0, stream>>>(q, k, vT, y, op, lpart);
    combineN<<<dim3(480), 256, 0, stream>>>(op, lpart, y);
    gemm_nt_m64<<<dim3(BT_/64, C_/128), 256, 0, stream>>>(y, wb + 3*NW, out);
}